// Round 3
// baseline (82.339 us; speedup 1.0000x reference)
//
#include <hip/hip_runtime.h>
#include <math.h>

#define NS 256
#define EMB 120
#define NBLK 60
#define MODES 16
#define NPH 8

__device__ __forceinline__ float2 cmul(float2 a, float2 b) {
    float2 r;
    r.x = fmaf(a.x, b.x, -(a.y * b.y));
    r.y = fmaf(a.x, b.y,   a.y * b.x);
    return r;
}

// Kernel A: x_emb = sigmoid(x@W.T+b); build V = U[:, :, 0:8] per sample.
__global__ __launch_bounds__(128) void emb_v_kernel(
    const float* __restrict__ x, const float* __restrict__ W,
    const float* __restrict__ bias, float* __restrict__ out_emb,
    float2* __restrict__ Vws)
{
    const int s = blockIdx.x;
    const int t = threadIdx.x;
    __shared__ float emb[EMB];
    __shared__ float ctA[NBLK], stA[NBLK], exA[NBLK], eyA[NBLK];

    if (t < EMB) {
        const float* xr = x + s * 64;
        const float* wr = W + t * 64;
        float acc = bias[t];
        #pragma unroll
        for (int k = 0; k < 64; ++k) acc = fmaf(xr[k], wr[k], acc);
        float e = 1.0f / (1.0f + expf(-acc));
        emb[t] = e;
        out_emb[s * EMB + t] = e;
    }
    __syncthreads();

    if (t < NBLK) {
        float th = emb[2 * t]     * 1.57079632679489662f;  // pi/2
        float ph = emb[2 * t + 1] * 6.28318530717958648f;  // 2*pi
        float st, ct, sp, cp;
        sincosf(th, &st, &ct);
        sincosf(ph, &sp, &cp);
        ctA[t] = ct; stA[t] = st; exA[t] = cp; eyA[t] = sp;
    }
    __syncthreads();

    if (t < NPH) {
        const int c = t;  // column 0..7
        float2 u[MODES];
        #pragma unroll
        for (int m = 0; m < MODES; ++m) {
            u[m].x = (m == c) ? 1.0f : 0.0f;
            u[m].y = 0.0f;
        }
        int bi = 0;
        #pragma unroll
        for (int d = 0; d < 8; ++d) {
            const int off = d & 1;
            const int nb = 8 - off;
            #pragma unroll
            for (int k = 0; k < nb; ++k) {
                float ct = ctA[bi], st = stA[bi], ex = exA[bi], ey = eyA[bi];
                ++bi;
                const int r0 = off + 2 * k;
                float2 u0 = u[r0], u1 = u[r0 + 1];
                float2 n0, n1;
                n0.x = ex * ct * u0.x - ey * ct * u0.y - st * u1.x;
                n0.y = ex * ct * u0.y + ey * ct * u0.x - st * u1.y;
                n1.x = ex * st * u0.x - ey * st * u0.y + ct * u1.x;
                n1.y = ex * st * u0.y + ey * st * u0.x + ct * u1.y;
                u[r0] = n0; u[r0 + 1] = n1;
            }
        }
        #pragma unroll
        for (int m = 0; m < MODES; ++m)
            Vws[(s * MODES + m) * NPH + c] = u[m];
    }
}

// Kernel B: block = 8x8 pair tile, 4 threads/pair (quarter-split Glynn).
// Phase 1: 4 threads/pair cooperatively compute G = Va^H Vb (2 rows each) -> LDS.
// Phase 2: each thread: full G -> regs, fix (d6,d7) by quarter, 32-term Gray
//          Glynn over bits 0..4 (fully unrolled, static indices), shfl reduce.
__global__ __launch_bounds__(256, 1) void perm_kernel(
    const float2* __restrict__ Vws, float* __restrict__ outK)
{
    __shared__ float2 sva[8][132];   // 8 samples x 128 float2, +4 pad (bank stagger)
    __shared__ float2 svb[8][132];
    __shared__ float2 sG[64][66];    // 64 pairs x 64 entries, stride 66 (16B-aligned rows)

    const int tid = threadIdx.x;
    const int ta = blockIdx.x >> 5;   // 0..31
    const int tb = blockIdx.x & 31;   // 0..31

    // Stage V tiles: 8 samples x 64 float4 each side.
    const float4* srcA = (const float4*)(Vws + (size_t)ta * 8 * 128);
    const float4* srcB = (const float4*)(Vws + (size_t)tb * 8 * 128);
    #pragma unroll
    for (int r = 0; r < 2; ++r) {
        int idx = r * 256 + tid;       // 0..511
        int row = idx >> 6;
        int c4  = idx & 63;
        *(float4*)&sva[row][c4 * 2] = srcA[idx];
        *(float4*)&svb[row][c4 * 2] = srcB[idx];
    }
    __syncthreads();

    const int p  = tid >> 2;    // pair 0..63
    const int q  = tid & 3;     // quarter 0..3
    const int pa = p >> 3;      // a within tile
    const int pb = p & 7;       // b within tile

    // ---- Phase 1: rows 2q, 2q+1 of G_p ----
    float2 Ga[2][8];
    #pragma unroll
    for (int i = 0; i < 2; ++i)
        #pragma unroll
        for (int j = 0; j < 8; ++j) { Ga[i][j].x = 0.f; Ga[i][j].y = 0.f; }

    #pragma unroll 1
    for (int m = 0; m < 16; ++m) {
        float4 va4 = *(const float4*)&sva[pa][m * 8 + 2 * q];
        float2 a0; a0.x = va4.x; a0.y = va4.y;
        float2 a1; a1.x = va4.z; a1.y = va4.w;
        float2 vb[8];
        #pragma unroll
        for (int jj = 0; jj < 4; ++jj) {
            float4 b4 = *(const float4*)&svb[pb][m * 8 + 2 * jj];
            vb[2 * jj].x     = b4.x; vb[2 * jj].y     = b4.y;
            vb[2 * jj + 1].x = b4.z; vb[2 * jj + 1].y = b4.w;
        }
        #pragma unroll
        for (int j = 0; j < 8; ++j) {
            Ga[0][j].x = fmaf(a0.x, vb[j].x, fmaf(a0.y, vb[j].y, Ga[0][j].x));
            Ga[0][j].y = fmaf(a0.x, vb[j].y, fmaf(-a0.y, vb[j].x, Ga[0][j].y));
            Ga[1][j].x = fmaf(a1.x, vb[j].x, fmaf(a1.y, vb[j].y, Ga[1][j].x));
            Ga[1][j].y = fmaf(a1.x, vb[j].y, fmaf(-a1.y, vb[j].x, Ga[1][j].y));
        }
    }
    #pragma unroll
    for (int i = 0; i < 2; ++i)
        #pragma unroll
        for (int jj = 0; jj < 4; ++jj) {
            float4 w;
            w.x = Ga[i][2 * jj].x;     w.y = Ga[i][2 * jj].y;
            w.z = Ga[i][2 * jj + 1].x; w.w = Ga[i][2 * jj + 1].y;
            *(float4*)&sG[p][(2 * q + i) * 8 + 2 * jj] = w;
        }
    __syncthreads();

    // ---- Phase 2: full G -> registers ----
    float2 G[8][8];
    #pragma unroll
    for (int i = 0; i < 8; ++i)
        #pragma unroll
        for (int jj = 0; jj < 4; ++jj) {
            float4 g4 = *(const float4*)&sG[p][i * 8 + 2 * jj];
            G[i][2 * jj].x     = g4.x; G[i][2 * jj].y     = g4.y;
            G[i][2 * jj + 1].x = g4.z; G[i][2 * jj + 1].y = g4.w;
        }

    // delta6/7 by quarter
    const float d6 = (q & 1) ? -1.f : 1.f;
    const float d7 = (q & 2) ? -1.f : 1.f;

    float2 rs[8];
    #pragma unroll
    for (int i = 0; i < 8; ++i) {
        float sx = G[i][0].x + G[i][1].x + G[i][2].x + G[i][3].x + G[i][4].x + G[i][5].x;
        float sy = G[i][0].y + G[i][1].y + G[i][2].y + G[i][3].y + G[i][4].y + G[i][5].y;
        sx = fmaf(d6, G[i][6].x, sx); sx = fmaf(d7, G[i][7].x, sx);
        sy = fmaf(d6, G[i][6].y, sy); sy = fmaf(d7, G[i][7].y, sy);
        rs[i].x = sx; rs[i].y = sy;
    }

    float2 acc;

#define PRODTREE(OUT) do {                                            \
        float2 p01 = cmul(rs[0], rs[1]);                              \
        float2 p23 = cmul(rs[2], rs[3]);                              \
        float2 p45 = cmul(rs[4], rs[5]);                              \
        float2 p67 = cmul(rs[6], rs[7]);                              \
        float2 q0  = cmul(p01, p23);                                  \
        float2 q1  = cmul(p45, p67);                                  \
        OUT = cmul(q0, q1);                                           \
    } while (0)

#define UPD(J, S) do {                                                \
        _Pragma("unroll")                                             \
        for (int i = 0; i < 8; ++i) {                                 \
            rs[i].x = fmaf((S), G[i][J].x, rs[i].x);                  \
            rs[i].y = fmaf((S), G[i][J].y, rs[i].y);                  \
        }                                                             \
    } while (0)

#define TERM(TS) do {                                                 \
        float2 pr; PRODTREE(pr);                                      \
        acc.x = fmaf((TS), pr.x, acc.x);                              \
        acc.y = fmaf((TS), pr.y, acc.y);                              \
    } while (0)

    PRODTREE(acc);                         // t=0, sign +
    UPD(1, -2.f); TERM(-1.f);              // t=1
    UPD(2, -2.f); TERM( 1.f);              // t=2
    UPD(1,  2.f); TERM(-1.f);              // t=3
    UPD(3, -2.f); TERM( 1.f);              // t=4
    UPD(1, -2.f); TERM(-1.f);              // t=5
    UPD(2,  2.f); TERM( 1.f);              // t=6
    UPD(1,  2.f); TERM(-1.f);              // t=7
    UPD(4, -2.f); TERM( 1.f);              // t=8
    UPD(1, -2.f); TERM(-1.f);              // t=9
    UPD(2, -2.f); TERM( 1.f);              // t=10
    UPD(1,  2.f); TERM(-1.f);              // t=11
    UPD(3,  2.f); TERM( 1.f);              // t=12
    UPD(1, -2.f); TERM(-1.f);              // t=13
    UPD(2,  2.f); TERM( 1.f);              // t=14
    UPD(1,  2.f); TERM(-1.f);              // t=15
    UPD(5, -2.f); TERM( 1.f);              // t=16
    UPD(1, -2.f); TERM(-1.f);              // t=17
    UPD(2, -2.f); TERM( 1.f);              // t=18
    UPD(1,  2.f); TERM(-1.f);              // t=19
    UPD(3, -2.f); TERM( 1.f);              // t=20
    UPD(1, -2.f); TERM(-1.f);              // t=21
    UPD(2,  2.f); TERM( 1.f);              // t=22
    UPD(1,  2.f); TERM(-1.f);              // t=23
    UPD(4,  2.f); TERM( 1.f);              // t=24
    UPD(1, -2.f); TERM(-1.f);              // t=25
    UPD(2, -2.f); TERM( 1.f);              // t=26
    UPD(1,  2.f); TERM(-1.f);              // t=27
    UPD(3,  2.f); TERM( 1.f);              // t=28
    UPD(1, -2.f); TERM(-1.f);              // t=29
    UPD(2,  2.f); TERM( 1.f);              // t=30
    UPD(1,  2.f); TERM(-1.f);              // t=31
#undef UPD
#undef TERM
#undef PRODTREE

    // quarter sign = d6*d7; reduce the 4 quarter lanes (consecutive lanes)
    const float sq = d6 * d7;
    float ax = acc.x * sq, ay = acc.y * sq;
    ax += __shfl_xor(ax, 1); ay += __shfl_xor(ay, 1);
    ax += __shfl_xor(ax, 2); ay += __shfl_xor(ay, 2);

    if (q == 0) {
        const int a = ta * 8 + pa;
        const int b = tb * 8 + pb;
        float K = fmaf(ax, ax, ay * ay) * (1.0f / 16384.0f);
        if (a == b) K = 1.0f;
        outK[a * 256 + b] = K;
    }
}

extern "C" void kernel_launch(void* const* d_in, const int* in_sizes, int n_in,
                              void* d_out, int out_size, void* d_ws, size_t ws_size,
                              hipStream_t stream) {
    const float* x    = (const float*)d_in[0];   // 256*64
    const float* W    = (const float*)d_in[1];   // 120*64
    const float* bias = (const float*)d_in[2];   // 120
    float* out     = (float*)d_out;
    float* out_emb = out;              // 256*120
    float* outK    = out + NS * EMB;   // 256*256
    float2* Vws    = (float2*)d_ws;    // 256*16*8 float2 = 256 KB

    emb_v_kernel<<<NS, 128, 0, stream>>>(x, W, bias, out_emb, Vws);
    perm_kernel<<<1024, 256, 0, stream>>>(Vws, outK);
}

// Round 4
// 81.700 us; speedup vs baseline: 1.0078x; 1.0078x over previous
//
#include <hip/hip_runtime.h>
#include <math.h>

#define NS 256
#define EMB 120
#define NBLK 60
#define MODES 16
#define NPH 8

typedef float v2f __attribute__((ext_vector_type(2)));

// complex mul: r = a*b   (2x v_pk_fma_f32 when matched)
__device__ __forceinline__ v2f cmul(v2f a, v2f b) {
    v2f axx = {a.x, a.x};
    v2f nyy = {-a.y, a.y};
    v2f byx = {b.y, b.x};
    return axx * b + nyy * byx;   // {ax*bx - ay*by, ax*by + ay*bx}
}
// r = conj(a)*b + c
__device__ __forceinline__ v2f cfma_conj(v2f a, v2f b, v2f c) {
    v2f axx = {a.x, a.x};
    v2f pyy = {a.y, -a.y};
    v2f byx = {b.y, b.x};
    return axx * b + (pyy * byx + c); // {ax*bx+ay*by+cx, ax*by-ay*bx+cy}
}

// Kernel A: x_emb = sigmoid(x@W.T+b); build V = U[:, :, 0:8] per sample.
__global__ __launch_bounds__(128) void emb_v_kernel(
    const float* __restrict__ x, const float* __restrict__ W,
    const float* __restrict__ bias, float* __restrict__ out_emb,
    float2* __restrict__ Vws)
{
    const int s = blockIdx.x;
    const int t = threadIdx.x;
    __shared__ float emb[EMB];
    __shared__ float ctA[NBLK], stA[NBLK], exA[NBLK], eyA[NBLK];

    if (t < EMB) {
        const float* xr = x + s * 64;
        const float* wr = W + t * 64;
        float acc = bias[t];
        #pragma unroll
        for (int k = 0; k < 64; ++k) acc = fmaf(xr[k], wr[k], acc);
        float e = 1.0f / (1.0f + expf(-acc));
        emb[t] = e;
        out_emb[s * EMB + t] = e;
    }
    __syncthreads();

    if (t < NBLK) {
        float th = emb[2 * t]     * 1.57079632679489662f;  // pi/2
        float ph = emb[2 * t + 1] * 6.28318530717958648f;  // 2*pi
        float st, ct, sp, cp;
        sincosf(th, &st, &ct);
        sincosf(ph, &sp, &cp);
        ctA[t] = ct; stA[t] = st; exA[t] = cp; eyA[t] = sp;
    }
    __syncthreads();

    if (t < NPH) {
        const int c = t;  // column 0..7
        float2 u[MODES];
        #pragma unroll
        for (int m = 0; m < MODES; ++m) {
            u[m].x = (m == c) ? 1.0f : 0.0f;
            u[m].y = 0.0f;
        }
        int bi = 0;
        #pragma unroll
        for (int d = 0; d < 8; ++d) {
            const int off = d & 1;
            const int nb = 8 - off;
            #pragma unroll
            for (int k = 0; k < nb; ++k) {
                float ct = ctA[bi], st = stA[bi], ex = exA[bi], ey = eyA[bi];
                ++bi;
                const int r0 = off + 2 * k;
                float2 u0 = u[r0], u1 = u[r0 + 1];
                float2 n0, n1;
                n0.x = ex * ct * u0.x - ey * ct * u0.y - st * u1.x;
                n0.y = ex * ct * u0.y + ey * ct * u0.x - st * u1.y;
                n1.x = ex * st * u0.x - ey * st * u0.y + ct * u1.x;
                n1.y = ex * st * u0.y + ey * st * u0.x + ct * u1.y;
                u[r0] = n0; u[r0 + 1] = n1;
            }
        }
        #pragma unroll
        for (int m = 0; m < MODES; ++m)
            Vws[(s * MODES + m) * NPH + c] = u[m];
    }
}

// Kernel B: block = 8x8 pair tile, 4 threads/pair (quarter-split Glynn),
// all complex math as packed float2 vectors (v_pk_fma_f32).
// __launch_bounds__(256,2): VGPR cap 256 -> no spill AND >=2 waves/SIMD.
// LDS: sG overlays sva/svb (union) -> 33.8 KB/block.
__global__ __launch_bounds__(256, 2) void perm_kernel(
    const float2* __restrict__ Vws, float* __restrict__ outK)
{
    __shared__ char smem[64 * 66 * sizeof(float2)];          // 33792 B
    float2 (*sva)[132] = (float2(*)[132])smem;               //  8448 B
    float2 (*svb)[132] = (float2(*)[132])(smem + 8448);      //  8448 B
    float2 (*sG)[66]   = (float2(*)[66])smem;                // overlays both

    const int tid = threadIdx.x;
    const int ta = blockIdx.x >> 5;   // 0..31
    const int tb = blockIdx.x & 31;   // 0..31

    // Stage V tiles: 8 samples x 64 float4 each side.
    const float4* srcA = (const float4*)(Vws + (size_t)ta * 8 * 128);
    const float4* srcB = (const float4*)(Vws + (size_t)tb * 8 * 128);
    #pragma unroll
    for (int r = 0; r < 2; ++r) {
        int idx = r * 256 + tid;       // 0..511
        int row = idx >> 6;
        int c4  = idx & 63;
        *(float4*)&sva[row][c4 * 2] = srcA[idx];
        *(float4*)&svb[row][c4 * 2] = srcB[idx];
    }
    __syncthreads();

    const int p  = tid >> 2;    // pair 0..63
    const int q  = tid & 3;     // quarter 0..3
    const int pa = p >> 3;      // a within tile
    const int pb = p & 7;       // b within tile

    // ---- Phase 1: rows 2q, 2q+1 of G_p = Va^H Vb ----
    v2f Ga[2][8];
    #pragma unroll
    for (int i = 0; i < 2; ++i)
        #pragma unroll
        for (int j = 0; j < 8; ++j) Ga[i][j] = (v2f){0.f, 0.f};

    #pragma unroll 1
    for (int m = 0; m < 16; ++m) {
        float4 va4 = *(const float4*)&sva[pa][m * 8 + 2 * q];
        v2f a0 = {va4.x, va4.y};
        v2f a1 = {va4.z, va4.w};
        v2f vb[8];
        #pragma unroll
        for (int jj = 0; jj < 4; ++jj) {
            float4 b4 = *(const float4*)&svb[pb][m * 8 + 2 * jj];
            vb[2 * jj]     = (v2f){b4.x, b4.y};
            vb[2 * jj + 1] = (v2f){b4.z, b4.w};
        }
        #pragma unroll
        for (int j = 0; j < 8; ++j) {
            Ga[0][j] = cfma_conj(a0, vb[j], Ga[0][j]);
            Ga[1][j] = cfma_conj(a1, vb[j], Ga[1][j]);
        }
    }
    __syncthreads();   // all sva/svb reads done before sG overwrites them

    #pragma unroll
    for (int i = 0; i < 2; ++i)
        #pragma unroll
        for (int jj = 0; jj < 4; ++jj) {
            float4 w;
            w.x = Ga[i][2 * jj].x;     w.y = Ga[i][2 * jj].y;
            w.z = Ga[i][2 * jj + 1].x; w.w = Ga[i][2 * jj + 1].y;
            *(float4*)&sG[p][(2 * q + i) * 8 + 2 * jj] = w;
        }
    __syncthreads();

    // ---- Phase 2: full G -> registers (broadcast reads, 2-way = free) ----
    v2f G[8][8];
    #pragma unroll
    for (int i = 0; i < 8; ++i)
        #pragma unroll
        for (int jj = 0; jj < 4; ++jj) {
            float4 g4 = *(const float4*)&sG[p][i * 8 + 2 * jj];
            G[i][2 * jj]     = (v2f){g4.x, g4.y};
            G[i][2 * jj + 1] = (v2f){g4.z, g4.w};
        }

    // delta6/7 fixed by quarter
    const float d6 = (q & 1) ? -1.f : 1.f;
    const float d7 = (q & 2) ? -1.f : 1.f;
    const v2f d6v = {d6, d6};
    const v2f d7v = {d7, d7};

    v2f rs[8];
    #pragma unroll
    for (int i = 0; i < 8; ++i) {
        v2f s = G[i][0] + G[i][1] + G[i][2] + G[i][3] + G[i][4] + G[i][5];
        s = d6v * G[i][6] + s;
        s = d7v * G[i][7] + s;
        rs[i] = s;
    }

    v2f acc;

#define PRODTREE(OUT) do {                                            \
        v2f p01 = cmul(rs[0], rs[1]);                                 \
        v2f p23 = cmul(rs[2], rs[3]);                                 \
        v2f p45 = cmul(rs[4], rs[5]);                                 \
        v2f p67 = cmul(rs[6], rs[7]);                                 \
        v2f q0  = cmul(p01, p23);                                     \
        v2f q1  = cmul(p45, p67);                                     \
        OUT = cmul(q0, q1);                                           \
    } while (0)

#define UPD(J, S) do {                                                \
        const v2f sv = {(S), (S)};                                    \
        _Pragma("unroll")                                             \
        for (int i = 0; i < 8; ++i) rs[i] = sv * G[i][J] + rs[i];     \
    } while (0)

#define TERM(TS) do {                                                 \
        float2 pr_; v2f pr; PRODTREE(pr); (void)pr_;                  \
        const v2f tv = {(TS), (TS)};                                  \
        acc = tv * pr + acc;                                          \
    } while (0)

    PRODTREE(acc);                         // t=0, sign +
    UPD(1, -2.f); TERM(-1.f);              // t=1
    UPD(2, -2.f); TERM( 1.f);              // t=2
    UPD(1,  2.f); TERM(-1.f);              // t=3
    UPD(3, -2.f); TERM( 1.f);              // t=4
    UPD(1, -2.f); TERM(-1.f);              // t=5
    UPD(2,  2.f); TERM( 1.f);              // t=6
    UPD(1,  2.f); TERM(-1.f);              // t=7
    UPD(4, -2.f); TERM( 1.f);              // t=8
    UPD(1, -2.f); TERM(-1.f);              // t=9
    UPD(2, -2.f); TERM( 1.f);              // t=10
    UPD(1,  2.f); TERM(-1.f);              // t=11
    UPD(3,  2.f); TERM( 1.f);              // t=12
    UPD(1, -2.f); TERM(-1.f);              // t=13
    UPD(2,  2.f); TERM( 1.f);              // t=14
    UPD(1,  2.f); TERM(-1.f);              // t=15
    UPD(5, -2.f); TERM( 1.f);              // t=16
    UPD(1, -2.f); TERM(-1.f);              // t=17
    UPD(2, -2.f); TERM( 1.f);              // t=18
    UPD(1,  2.f); TERM(-1.f);              // t=19
    UPD(3, -2.f); TERM( 1.f);              // t=20
    UPD(1, -2.f); TERM(-1.f);              // t=21
    UPD(2,  2.f); TERM( 1.f);              // t=22
    UPD(1,  2.f); TERM(-1.f);              // t=23
    UPD(4,  2.f); TERM( 1.f);              // t=24
    UPD(1, -2.f); TERM(-1.f);              // t=25
    UPD(2, -2.f); TERM( 1.f);              // t=26
    UPD(1,  2.f); TERM(-1.f);              // t=27
    UPD(3,  2.f); TERM( 1.f);              // t=28
    UPD(1, -2.f); TERM(-1.f);              // t=29
    UPD(2,  2.f); TERM( 1.f);              // t=30
    UPD(1,  2.f); TERM(-1.f);              // t=31
#undef UPD
#undef TERM
#undef PRODTREE

    // quarter sign = d6*d7; reduce 4 quarter lanes (consecutive -> DPP shfl)
    const float sq = d6 * d7;
    float ax = acc.x * sq, ay = acc.y * sq;
    ax += __shfl_xor(ax, 1); ay += __shfl_xor(ay, 1);
    ax += __shfl_xor(ax, 2); ay += __shfl_xor(ay, 2);

    if (q == 0) {
        const int a = ta * 8 + pa;
        const int b = tb * 8 + pb;
        float K = fmaf(ax, ax, ay * ay) * (1.0f / 16384.0f);
        if (a == b) K = 1.0f;
        outK[a * 256 + b] = K;
    }
}

extern "C" void kernel_launch(void* const* d_in, const int* in_sizes, int n_in,
                              void* d_out, int out_size, void* d_ws, size_t ws_size,
                              hipStream_t stream) {
    const float* x    = (const float*)d_in[0];   // 256*64
    const float* W    = (const float*)d_in[1];   // 120*64
    const float* bias = (const float*)d_in[2];   // 120
    float* out     = (float*)d_out;
    float* out_emb = out;              // 256*120
    float* outK    = out + NS * EMB;   // 256*256
    float2* Vws    = (float2*)d_ws;    // 256*16*8 float2 = 256 KB

    emb_v_kernel<<<NS, 128, 0, stream>>>(x, W, bias, out_emb, Vws);
    perm_kernel<<<1024, 256, 0, stream>>>(Vws, outK);
}

// Round 5
// 79.620 us; speedup vs baseline: 1.0342x; 1.0261x over previous
//
#include <hip/hip_runtime.h>
#include <math.h>

#define NS 256
#define EMB 120
#define NBLK 60
#define MODES 16
#define NPH 8

typedef float v2f __attribute__((ext_vector_type(2)));

// complex mul (2x v_pk_fma_f32 with op_sel/neg modifiers)
__device__ __forceinline__ v2f cmul(v2f a, v2f b) {
    v2f axx = {a.x, a.x};
    v2f nyy = {-a.y, a.y};
    v2f byx = {b.y, b.x};
    return axx * b + nyy * byx;   // {ax*bx - ay*by, ax*by + ay*bx}
}
// r = conj(a)*b + c
__device__ __forceinline__ v2f cfma_conj(v2f a, v2f b, v2f c) {
    v2f axx = {a.x, a.x};
    v2f pyy = {a.y, -a.y};
    v2f byx = {b.y, b.x};
    return axx * b + (pyy * byx + c); // {ax*bx+ay*by+cx, ax*by-ay*bx+cy}
}

// Kernel A: x_emb = sigmoid(x@W.T+b); build V = U[:, :, 0:8] per sample.
__global__ __launch_bounds__(128) void emb_v_kernel(
    const float* __restrict__ x, const float* __restrict__ W,
    const float* __restrict__ bias, float* __restrict__ out_emb,
    float2* __restrict__ Vws)
{
    const int s = blockIdx.x;
    const int t = threadIdx.x;
    __shared__ float emb[EMB];
    __shared__ float ctA[NBLK], stA[NBLK], exA[NBLK], eyA[NBLK];

    if (t < EMB) {
        const float* xr = x + s * 64;
        const float* wr = W + t * 64;
        float acc = bias[t];
        #pragma unroll
        for (int k = 0; k < 64; ++k) acc = fmaf(xr[k], wr[k], acc);
        float e = 1.0f / (1.0f + expf(-acc));
        emb[t] = e;
        out_emb[s * EMB + t] = e;
    }
    __syncthreads();

    if (t < NBLK) {
        float th = emb[2 * t]     * 1.57079632679489662f;  // pi/2
        float ph = emb[2 * t + 1] * 6.28318530717958648f;  // 2*pi
        float st, ct, sp, cp;
        sincosf(th, &st, &ct);
        sincosf(ph, &sp, &cp);
        ctA[t] = ct; stA[t] = st; exA[t] = cp; eyA[t] = sp;
    }
    __syncthreads();

    if (t < NPH) {
        const int c = t;  // column 0..7
        float2 u[MODES];
        #pragma unroll
        for (int m = 0; m < MODES; ++m) {
            u[m].x = (m == c) ? 1.0f : 0.0f;
            u[m].y = 0.0f;
        }
        int bi = 0;
        #pragma unroll
        for (int d = 0; d < 8; ++d) {
            const int off = d & 1;
            const int nb = 8 - off;
            #pragma unroll
            for (int k = 0; k < nb; ++k) {
                float ct = ctA[bi], st = stA[bi], ex = exA[bi], ey = eyA[bi];
                ++bi;
                const int r0 = off + 2 * k;
                float2 u0 = u[r0], u1 = u[r0 + 1];
                float2 n0, n1;
                n0.x = ex * ct * u0.x - ey * ct * u0.y - st * u1.x;
                n0.y = ex * ct * u0.y + ey * ct * u0.x - st * u1.y;
                n1.x = ex * st * u0.x - ey * st * u0.y + ct * u1.x;
                n1.y = ex * st * u0.y + ey * st * u0.x + ct * u1.y;
                u[r0] = n0; u[r0 + 1] = n1;
            }
        }
        #pragma unroll
        for (int m = 0; m < MODES; ++m)
            Vws[(s * MODES + m) * NPH + c] = u[m];
    }
}

// Kernel B: 4 threads/pair = (row-half h = sub&1) x (delta7-half e = sub>>1).
// Each thread: builds 2 rows of G = Va^H Vb (registers only, no sG LDS),
// swaps 2 rows with its xor-2 partner (DPP), holds G[4][8] = 64 VGPRs,
// walks 64-term Gray Glynn over d1..d6 (unrolled, static cols/signs);
// cross-h product via shfl_xor(1), delta7 halves combined via shfl_xor(2).
// __launch_bounds__(256,4): VGPR cap 128 -> 4 waves/SIMD, no big live set.
__global__ __launch_bounds__(256, 4) void perm_kernel(
    const float2* __restrict__ Vws, float* __restrict__ outK)
{
    __shared__ float2 sva[8][132];   // 8 samples x 128 f2, +4 pad
    __shared__ float2 svb[8][132];

    const int tid = threadIdx.x;
    const int ta = blockIdx.x >> 5;   // 0..31
    const int tb = blockIdx.x & 31;   // 0..31

    const float4* srcA = (const float4*)(Vws + (size_t)ta * 8 * 128);
    const float4* srcB = (const float4*)(Vws + (size_t)tb * 8 * 128);
    #pragma unroll
    for (int r = 0; r < 2; ++r) {
        int idx = r * 256 + tid;       // 0..511
        int row = idx >> 6;
        int c4  = idx & 63;
        *(float4*)&sva[row][c4 * 2] = srcA[idx];
        *(float4*)&svb[row][c4 * 2] = srcB[idx];
    }
    __syncthreads();

    const int p   = tid >> 2;    // pair 0..63
    const int sub = tid & 3;
    const int h   = sub & 1;     // row half: rows 4h..4h+3
    const int e   = sub >> 1;    // delta7 half
    const int pa  = p >> 3;
    const int pb  = p & 7;

    // ---- build own 2 rows: rows 4h+2e, 4h+2e+1 of G ----
    v2f Go[2][8];
    #pragma unroll
    for (int i = 0; i < 2; ++i)
        #pragma unroll
        for (int j = 0; j < 8; ++j) Go[i][j] = (v2f){0.f, 0.f};

    #pragma unroll 2
    for (int m = 0; m < 16; ++m) {
        float4 va4 = *(const float4*)&sva[pa][m * 8 + 4 * h + 2 * e];
        v2f a0 = {va4.x, va4.y};
        v2f a1 = {va4.z, va4.w};
        v2f vb[8];
        #pragma unroll
        for (int jj = 0; jj < 4; ++jj) {
            float4 b4 = *(const float4*)&svb[pb][m * 8 + 2 * jj];
            vb[2 * jj]     = (v2f){b4.x, b4.y};
            vb[2 * jj + 1] = (v2f){b4.z, b4.w};
        }
        #pragma unroll
        for (int j = 0; j < 8; ++j) {
            Go[0][j] = cfma_conj(a0, vb[j], Go[0][j]);
            Go[1][j] = cfma_conj(a1, vb[j], Go[1][j]);
        }
    }

    // ---- exchange with delta-partner (same h, other e): get other 2 rows ----
    // Row ORDER is irrelevant (product over rows is order-invariant).
    v2f Gp[2][8];
    #pragma unroll
    for (int i = 0; i < 2; ++i)
        #pragma unroll
        for (int j = 0; j < 8; ++j) {
            Gp[i][j].x = __shfl_xor(Go[i][j].x, 2);
            Gp[i][j].y = __shfl_xor(Go[i][j].y, 2);
        }

    // ---- rs init: delta = (+1,...,+1, sgn_e) ----
    const float sgn = 1.0f - 2.0f * (float)e;
    const v2f sgnv = {sgn, sgn};
    v2f rs[4];
    #pragma unroll
    for (int r = 0; r < 2; ++r) {
        {
            v2f s = ((Go[r][0] + Go[r][1]) + (Go[r][2] + Go[r][3]))
                  + ((Go[r][4] + Go[r][5]) + Go[r][6]);
            rs[r] = sgnv * Go[r][7] + s;
        }
        {
            v2f s = ((Gp[r][0] + Gp[r][1]) + (Gp[r][2] + Gp[r][3]))
                  + ((Gp[r][4] + Gp[r][5]) + Gp[r][6]);
            rs[2 + r] = sgnv * Gp[r][7] + s;
        }
    }

    v2f acc;

#define TREE(OUT) do {                                                \
        v2f t01 = cmul(rs[0], rs[1]);                                 \
        v2f t23 = cmul(rs[2], rs[3]);                                 \
        v2f half = cmul(t01, t23);                                    \
        v2f oth;                                                      \
        oth.x = __shfl_xor(half.x, 1);                                \
        oth.y = __shfl_xor(half.y, 1);                                \
        OUT = cmul(half, oth);                                        \
    } while (0)

#define UPD(J, S) do {                                                \
        const v2f sv = {(S), (S)};                                    \
        rs[0] = sv * Go[0][J] + rs[0];                                \
        rs[1] = sv * Go[1][J] + rs[1];                                \
        rs[2] = sv * Gp[0][J] + rs[2];                                \
        rs[3] = sv * Gp[1][J] + rs[3];                                \
    } while (0)

#define TERM(TS) do {                                                 \
        v2f fullp; TREE(fullp);                                       \
        const v2f tv = {(TS), (TS)};                                  \
        acc = tv * fullp + acc;                                       \
    } while (0)

    TREE(acc);                              // t=0, sign +
    UPD(1, -2.f); TERM(-1.f);               // t=1
    UPD(2, -2.f); TERM( 1.f);               // t=2
    UPD(1,  2.f); TERM(-1.f);               // t=3
    UPD(3, -2.f); TERM( 1.f);               // t=4
    UPD(1, -2.f); TERM(-1.f);               // t=5
    UPD(2,  2.f); TERM( 1.f);               // t=6
    UPD(1,  2.f); TERM(-1.f);               // t=7
    UPD(4, -2.f); TERM( 1.f);               // t=8
    UPD(1, -2.f); TERM(-1.f);               // t=9
    UPD(2, -2.f); TERM( 1.f);               // t=10
    UPD(1,  2.f); TERM(-1.f);               // t=11
    UPD(3,  2.f); TERM( 1.f);               // t=12
    UPD(1, -2.f); TERM(-1.f);               // t=13
    UPD(2,  2.f); TERM( 1.f);               // t=14
    UPD(1,  2.f); TERM(-1.f);               // t=15
    UPD(5, -2.f); TERM( 1.f);               // t=16
    UPD(1, -2.f); TERM(-1.f);               // t=17
    UPD(2, -2.f); TERM( 1.f);               // t=18
    UPD(1,  2.f); TERM(-1.f);               // t=19
    UPD(3, -2.f); TERM( 1.f);               // t=20
    UPD(1, -2.f); TERM(-1.f);               // t=21
    UPD(2,  2.f); TERM( 1.f);               // t=22
    UPD(1,  2.f); TERM(-1.f);               // t=23
    UPD(4,  2.f); TERM( 1.f);               // t=24
    UPD(1, -2.f); TERM(-1.f);               // t=25
    UPD(2, -2.f); TERM( 1.f);               // t=26
    UPD(1,  2.f); TERM(-1.f);               // t=27
    UPD(3,  2.f); TERM( 1.f);               // t=28
    UPD(1, -2.f); TERM(-1.f);               // t=29
    UPD(2,  2.f); TERM( 1.f);               // t=30
    UPD(1,  2.f); TERM(-1.f);               // t=31
    UPD(6, -2.f); TERM( 1.f);               // t=32
    UPD(1, -2.f); TERM(-1.f);               // t=33
    UPD(2, -2.f); TERM( 1.f);               // t=34
    UPD(1,  2.f); TERM(-1.f);               // t=35
    UPD(3, -2.f); TERM( 1.f);               // t=36
    UPD(1, -2.f); TERM(-1.f);               // t=37
    UPD(2,  2.f); TERM( 1.f);               // t=38
    UPD(1,  2.f); TERM(-1.f);               // t=39
    UPD(4, -2.f); TERM( 1.f);               // t=40
    UPD(1, -2.f); TERM(-1.f);               // t=41
    UPD(2, -2.f); TERM( 1.f);               // t=42
    UPD(1,  2.f); TERM(-1.f);               // t=43
    UPD(3,  2.f); TERM( 1.f);               // t=44
    UPD(1, -2.f); TERM(-1.f);               // t=45
    UPD(2,  2.f); TERM( 1.f);               // t=46
    UPD(1,  2.f); TERM(-1.f);               // t=47
    UPD(5,  2.f); TERM( 1.f);               // t=48
    UPD(1, -2.f); TERM(-1.f);               // t=49
    UPD(2, -2.f); TERM( 1.f);               // t=50
    UPD(1,  2.f); TERM(-1.f);               // t=51
    UPD(3, -2.f); TERM( 1.f);               // t=52
    UPD(1, -2.f); TERM(-1.f);               // t=53
    UPD(2,  2.f); TERM( 1.f);               // t=54
    UPD(1,  2.f); TERM(-1.f);               // t=55
    UPD(4,  2.f); TERM( 1.f);               // t=56
    UPD(1, -2.f); TERM(-1.f);               // t=57
    UPD(2, -2.f); TERM( 1.f);               // t=58
    UPD(1,  2.f); TERM(-1.f);               // t=59
    UPD(3,  2.f); TERM( 1.f);               // t=60
    UPD(1, -2.f); TERM(-1.f);               // t=61
    UPD(2,  2.f); TERM( 1.f);               // t=62
    UPD(1,  2.f); TERM(-1.f);               // t=63
#undef UPD
#undef TERM
#undef TREE

    // fold delta7 sign, then combine the two delta-halves (xor 2)
    float ax = sgn * acc.x, ay = sgn * acc.y;
    ax += __shfl_xor(ax, 2);
    ay += __shfl_xor(ay, 2);

    if (sub == 0) {
        const int a = ta * 8 + pa;
        const int b = tb * 8 + pb;
        float K = fmaf(ax, ax, ay * ay) * (1.0f / 16384.0f);
        if (a == b) K = 1.0f;
        outK[a * 256 + b] = K;
    }
}

extern "C" void kernel_launch(void* const* d_in, const int* in_sizes, int n_in,
                              void* d_out, int out_size, void* d_ws, size_t ws_size,
                              hipStream_t stream) {
    const float* x    = (const float*)d_in[0];   // 256*64
    const float* W    = (const float*)d_in[1];   // 120*64
    const float* bias = (const float*)d_in[2];   // 120
    float* out     = (float*)d_out;
    float* out_emb = out;              // 256*120
    float* outK    = out + NS * EMB;   // 256*256
    float2* Vws    = (float2*)d_ws;    // 256*16*8 float2 = 256 KB

    emb_v_kernel<<<NS, 128, 0, stream>>>(x, W, bias, out_emb, Vws);
    perm_kernel<<<1024, 256, 0, stream>>>(Vws, outK);
}

// Round 6
// 76.549 us; speedup vs baseline: 1.0756x; 1.0401x over previous
//
#include <hip/hip_runtime.h>
#include <math.h>

#define NS 256
#define EMB 120
#define NBLK 60
#define MODES 16
#define NPH 8

typedef float v2f __attribute__((ext_vector_type(2)));

// complex mul
__device__ __forceinline__ v2f cmul(v2f a, v2f b) {
    v2f axx = {a.x, a.x};
    v2f nyy = {-a.y, a.y};
    v2f byx = {b.y, b.x};
    return axx * b + nyy * byx;   // {ax*bx - ay*by, ax*by + ay*bx}
}
// r = conj(a)*b + c
__device__ __forceinline__ v2f cfma_conj(v2f a, v2f b, v2f c) {
    v2f axx = {a.x, a.x};
    v2f pyy = {a.y, -a.y};
    v2f byx = {b.y, b.x};
    return axx * b + (pyy * byx + c);
}

// Cross-lane xor within quad via DPP quad_perm (VALU, not LDS pipe).
// xor1: [1,0,3,2] -> ctrl 0xB1 ; xor2: [2,3,0,1] -> ctrl 0x4E
__device__ __forceinline__ float dpp_xor1(float x) {
    return __builtin_bit_cast(float,
        __builtin_amdgcn_mov_dpp(__builtin_bit_cast(int, x), 0xB1, 0xF, 0xF, true));
}
__device__ __forceinline__ float dpp_xor2(float x) {
    return __builtin_bit_cast(float,
        __builtin_amdgcn_mov_dpp(__builtin_bit_cast(int, x), 0x4E, 0xF, 0xF, true));
}

// Kernel A: x_emb = sigmoid(x@W.T+b); build V = U[:, :, 0:8] per sample.
__global__ __launch_bounds__(128) void emb_v_kernel(
    const float* __restrict__ x, const float* __restrict__ W,
    const float* __restrict__ bias, float* __restrict__ out_emb,
    float2* __restrict__ Vws)
{
    const int s = blockIdx.x;
    const int t = threadIdx.x;
    __shared__ float emb[EMB];
    __shared__ float ctA[NBLK], stA[NBLK], exA[NBLK], eyA[NBLK];

    if (t < EMB) {
        const float* xr = x + s * 64;
        const float* wr = W + t * 64;
        float acc = bias[t];
        #pragma unroll
        for (int k = 0; k < 64; ++k) acc = fmaf(xr[k], wr[k], acc);
        float e = 1.0f / (1.0f + expf(-acc));
        emb[t] = e;
        out_emb[s * EMB + t] = e;
    }
    __syncthreads();

    if (t < NBLK) {
        float th = emb[2 * t]     * 1.57079632679489662f;  // pi/2
        float ph = emb[2 * t + 1] * 6.28318530717958648f;  // 2*pi
        float st, ct, sp, cp;
        sincosf(th, &st, &ct);
        sincosf(ph, &sp, &cp);
        ctA[t] = ct; stA[t] = st; exA[t] = cp; eyA[t] = sp;
    }
    __syncthreads();

    if (t < NPH) {
        const int c = t;  // column 0..7
        float2 u[MODES];
        #pragma unroll
        for (int m = 0; m < MODES; ++m) {
            u[m].x = (m == c) ? 1.0f : 0.0f;
            u[m].y = 0.0f;
        }
        int bi = 0;
        #pragma unroll
        for (int d = 0; d < 8; ++d) {
            const int off = d & 1;
            const int nb = 8 - off;
            #pragma unroll
            for (int k = 0; k < nb; ++k) {
                float ct = ctA[bi], st = stA[bi], ex = exA[bi], ey = eyA[bi];
                ++bi;
                const int r0 = off + 2 * k;
                float2 u0 = u[r0], u1 = u[r0 + 1];
                float2 n0, n1;
                n0.x = ex * ct * u0.x - ey * ct * u0.y - st * u1.x;
                n0.y = ex * ct * u0.y + ey * ct * u0.x - st * u1.y;
                n1.x = ex * st * u0.x - ey * st * u0.y + ct * u1.x;
                n1.y = ex * st * u0.y + ey * st * u0.x + ct * u1.y;
                u[r0] = n0; u[r0 + 1] = n1;
            }
        }
        #pragma unroll
        for (int m = 0; m < MODES; ++m)
            Vws[(s * MODES + m) * NPH + c] = u[m];
    }
}

// Kernel B: upper-triangular tiles only (K is symmetric: G(b,a)=G(a,b)^H,
// perm(A^H)=conj(perm A) -> |perm|^2 symmetric). 528 blocks of 8x8 pairs.
// 4 threads/pair = (row-half h) x (delta7-half e); all cross-lane via DPP
// quad_perm (VALU) -- no ds_bpermute in the hot loop.
__global__ __launch_bounds__(256, 4) void perm_kernel(
    const float2* __restrict__ Vws, float* __restrict__ outK)
{
    __shared__ float2 sva[8][132];
    __shared__ float2 svb[8][132];

    // triangular decode: blockIdx -> (ta, tb), ta <= tb, row start S(t)=t(65-t)/2
    const int L = blockIdx.x;
    int t = (int)((65.0f - sqrtf(4225.0f - 8.0f * (float)L)) * 0.5f);
    while (t * (65 - t) / 2 > L) --t;
    while ((t + 1) * (65 - (t + 1)) / 2 <= L) ++t;
    const int ta = t;
    const int tb = ta + (L - t * (65 - t) / 2);

    const int tid = threadIdx.x;
    const float4* srcA = (const float4*)(Vws + (size_t)ta * 8 * 128);
    const float4* srcB = (const float4*)(Vws + (size_t)tb * 8 * 128);
    #pragma unroll
    for (int r = 0; r < 2; ++r) {
        int idx = r * 256 + tid;       // 0..511
        int row = idx >> 6;
        int c4  = idx & 63;
        *(float4*)&sva[row][c4 * 2] = srcA[idx];
        *(float4*)&svb[row][c4 * 2] = srcB[idx];
    }
    __syncthreads();

    const int p   = tid >> 2;    // pair 0..63 (quad-aligned lanes)
    const int sub = tid & 3;
    const int h   = sub & 1;     // row half
    const int e   = sub >> 1;    // delta7 half
    const int pa  = p >> 3;
    const int pb  = p & 7;

    // ---- build own 2 rows: rows 4h+2e, 4h+2e+1 of G = Va^H Vb ----
    v2f Go[2][8];
    #pragma unroll
    for (int i = 0; i < 2; ++i)
        #pragma unroll
        for (int j = 0; j < 8; ++j) Go[i][j] = (v2f){0.f, 0.f};

    #pragma unroll 2
    for (int m = 0; m < 16; ++m) {
        float4 va4 = *(const float4*)&sva[pa][m * 8 + 4 * h + 2 * e];
        v2f a0 = {va4.x, va4.y};
        v2f a1 = {va4.z, va4.w};
        v2f vb[8];
        #pragma unroll
        for (int jj = 0; jj < 4; ++jj) {
            float4 b4 = *(const float4*)&svb[pb][m * 8 + 2 * jj];
            vb[2 * jj]     = (v2f){b4.x, b4.y};
            vb[2 * jj + 1] = (v2f){b4.z, b4.w};
        }
        #pragma unroll
        for (int j = 0; j < 8; ++j) {
            Go[0][j] = cfma_conj(a0, vb[j], Go[0][j]);
            Go[1][j] = cfma_conj(a1, vb[j], Go[1][j]);
        }
    }

    // ---- exchange 2 rows with delta-partner (xor 2) via DPP ----
    v2f Gp[2][8];
    #pragma unroll
    for (int i = 0; i < 2; ++i)
        #pragma unroll
        for (int j = 0; j < 8; ++j) {
            Gp[i][j].x = dpp_xor2(Go[i][j].x);
            Gp[i][j].y = dpp_xor2(Go[i][j].y);
        }

    // ---- rs init: delta = (+1,...,+1, sgn_e) ----
    const float sgn = 1.0f - 2.0f * (float)e;
    const v2f sgnv = {sgn, sgn};
    v2f rs[4];
    #pragma unroll
    for (int r = 0; r < 2; ++r) {
        {
            v2f s = ((Go[r][0] + Go[r][1]) + (Go[r][2] + Go[r][3]))
                  + ((Go[r][4] + Go[r][5]) + Go[r][6]);
            rs[r] = sgnv * Go[r][7] + s;
        }
        {
            v2f s = ((Gp[r][0] + Gp[r][1]) + (Gp[r][2] + Gp[r][3]))
                  + ((Gp[r][4] + Gp[r][5]) + Gp[r][6]);
            rs[2 + r] = sgnv * Gp[r][7] + s;
        }
    }

    v2f acc;

#define TREE(OUT) do {                                                \
        v2f t01 = cmul(rs[0], rs[1]);                                 \
        v2f t23 = cmul(rs[2], rs[3]);                                 \
        v2f half = cmul(t01, t23);                                    \
        v2f oth;                                                      \
        oth.x = dpp_xor1(half.x);                                     \
        oth.y = dpp_xor1(half.y);                                     \
        OUT = cmul(half, oth);                                        \
    } while (0)

#define UPD(J, S) do {                                                \
        const v2f sv = {(S), (S)};                                    \
        rs[0] = sv * Go[0][J] + rs[0];                                \
        rs[1] = sv * Go[1][J] + rs[1];                                \
        rs[2] = sv * Gp[0][J] + rs[2];                                \
        rs[3] = sv * Gp[1][J] + rs[3];                                \
    } while (0)

#define TERM(TS) do {                                                 \
        v2f fullp; TREE(fullp);                                       \
        const v2f tv = {(TS), (TS)};                                  \
        acc = tv * fullp + acc;                                       \
    } while (0)

    TREE(acc);                              // t=0, sign +
    UPD(1, -2.f); TERM(-1.f);               // t=1
    UPD(2, -2.f); TERM( 1.f);               // t=2
    UPD(1,  2.f); TERM(-1.f);               // t=3
    UPD(3, -2.f); TERM( 1.f);               // t=4
    UPD(1, -2.f); TERM(-1.f);               // t=5
    UPD(2,  2.f); TERM( 1.f);               // t=6
    UPD(1,  2.f); TERM(-1.f);               // t=7
    UPD(4, -2.f); TERM( 1.f);               // t=8
    UPD(1, -2.f); TERM(-1.f);               // t=9
    UPD(2, -2.f); TERM( 1.f);               // t=10
    UPD(1,  2.f); TERM(-1.f);               // t=11
    UPD(3,  2.f); TERM( 1.f);               // t=12
    UPD(1, -2.f); TERM(-1.f);               // t=13
    UPD(2,  2.f); TERM( 1.f);               // t=14
    UPD(1,  2.f); TERM(-1.f);               // t=15
    UPD(5, -2.f); TERM( 1.f);               // t=16
    UPD(1, -2.f); TERM(-1.f);               // t=17
    UPD(2, -2.f); TERM( 1.f);               // t=18
    UPD(1,  2.f); TERM(-1.f);               // t=19
    UPD(3, -2.f); TERM( 1.f);               // t=20
    UPD(1, -2.f); TERM(-1.f);               // t=21
    UPD(2,  2.f); TERM( 1.f);               // t=22
    UPD(1,  2.f); TERM(-1.f);               // t=23
    UPD(4,  2.f); TERM( 1.f);               // t=24
    UPD(1, -2.f); TERM(-1.f);               // t=25
    UPD(2, -2.f); TERM( 1.f);               // t=26
    UPD(1,  2.f); TERM(-1.f);               // t=27
    UPD(3,  2.f); TERM( 1.f);               // t=28
    UPD(1, -2.f); TERM(-1.f);               // t=29
    UPD(2,  2.f); TERM( 1.f);               // t=30
    UPD(1,  2.f); TERM(-1.f);               // t=31
    UPD(6, -2.f); TERM( 1.f);               // t=32
    UPD(1, -2.f); TERM(-1.f);               // t=33
    UPD(2, -2.f); TERM( 1.f);               // t=34
    UPD(1,  2.f); TERM(-1.f);               // t=35
    UPD(3, -2.f); TERM( 1.f);               // t=36
    UPD(1, -2.f); TERM(-1.f);               // t=37
    UPD(2,  2.f); TERM( 1.f);               // t=38
    UPD(1,  2.f); TERM(-1.f);               // t=39
    UPD(4, -2.f); TERM( 1.f);               // t=40
    UPD(1, -2.f); TERM(-1.f);               // t=41
    UPD(2, -2.f); TERM( 1.f);               // t=42
    UPD(1,  2.f); TERM(-1.f);               // t=43
    UPD(3,  2.f); TERM( 1.f);               // t=44
    UPD(1, -2.f); TERM(-1.f);               // t=45
    UPD(2,  2.f); TERM( 1.f);               // t=46
    UPD(1,  2.f); TERM(-1.f);               // t=47
    UPD(5,  2.f); TERM( 1.f);               // t=48
    UPD(1, -2.f); TERM(-1.f);               // t=49
    UPD(2, -2.f); TERM( 1.f);               // t=50
    UPD(1,  2.f); TERM(-1.f);               // t=51
    UPD(3, -2.f); TERM( 1.f);               // t=52
    UPD(1, -2.f); TERM(-1.f);               // t=53
    UPD(2,  2.f); TERM( 1.f);               // t=54
    UPD(1,  2.f); TERM(-1.f);               // t=55
    UPD(4,  2.f); TERM( 1.f);               // t=56
    UPD(1, -2.f); TERM(-1.f);               // t=57
    UPD(2, -2.f); TERM( 1.f);               // t=58
    UPD(1,  2.f); TERM(-1.f);               // t=59
    UPD(3,  2.f); TERM( 1.f);               // t=60
    UPD(1, -2.f); TERM(-1.f);               // t=61
    UPD(2,  2.f); TERM( 1.f);               // t=62
    UPD(1,  2.f); TERM(-1.f);               // t=63
#undef UPD
#undef TERM
#undef TREE

    // fold delta7 sign, then combine the two delta-halves (xor 2, DPP)
    float ax = sgn * acc.x, ay = sgn * acc.y;
    ax += dpp_xor2(ax);
    ay += dpp_xor2(ay);

    if (sub == 0) {
        const int a = ta * 8 + pa;
        const int b = tb * 8 + pb;
        float K = fmaf(ax, ax, ay * ay) * (1.0f / 16384.0f);
        if (a == b) K = 1.0f;
        outK[a * 256 + b] = K;
        outK[b * 256 + a] = K;   // Hermitian symmetry
    }
}

extern "C" void kernel_launch(void* const* d_in, const int* in_sizes, int n_in,
                              void* d_out, int out_size, void* d_ws, size_t ws_size,
                              hipStream_t stream) {
    const float* x    = (const float*)d_in[0];   // 256*64
    const float* W    = (const float*)d_in[1];   // 120*64
    const float* bias = (const float*)d_in[2];   // 120
    float* out     = (float*)d_out;
    float* out_emb = out;              // 256*120
    float* outK    = out + NS * EMB;   // 256*256
    float2* Vws    = (float2*)d_ws;    // 256*16*8 float2 = 256 KB

    emb_v_kernel<<<NS, 128, 0, stream>>>(x, W, bias, out_emb, Vws);
    perm_kernel<<<528, 256, 0, stream>>>(Vws, outK);
}

// Round 7
// 76.277 us; speedup vs baseline: 1.0795x; 1.0036x over previous
//
#include <hip/hip_runtime.h>
#include <math.h>

#define NS 256
#define EMB 120
#define NBLK 60
#define MODES 16
#define NPH 8

typedef float v2f __attribute__((ext_vector_type(2)));

// complex mul
__device__ __forceinline__ v2f cmul(v2f a, v2f b) {
    v2f axx = {a.x, a.x};
    v2f nyy = {-a.y, a.y};
    v2f byx = {b.y, b.x};
    return axx * b + nyy * byx;   // {ax*bx - ay*by, ax*by + ay*bx}
}
// r = conj(a)*b + c
__device__ __forceinline__ v2f cfma_conj(v2f a, v2f b, v2f c) {
    v2f axx = {a.x, a.x};
    v2f pyy = {a.y, -a.y};
    v2f byx = {b.y, b.x};
    return axx * b + (pyy * byx + c);
}

// Cross-lane xor within quad via DPP quad_perm (VALU, not LDS pipe).
// xor1: [1,0,3,2] -> ctrl 0xB1 ; xor2: [2,3,0,1] -> ctrl 0x4E
__device__ __forceinline__ float dpp_xor1(float x) {
    return __builtin_bit_cast(float,
        __builtin_amdgcn_mov_dpp(__builtin_bit_cast(int, x), 0xB1, 0xF, 0xF, true));
}
__device__ __forceinline__ float dpp_xor2(float x) {
    return __builtin_bit_cast(float,
        __builtin_amdgcn_mov_dpp(__builtin_bit_cast(int, x), 0x4E, 0xF, 0xF, true));
}

// Kernel A: x_emb = sigmoid(x@W.T+b); build V = U[:, :, 0:8] per sample.
__global__ __launch_bounds__(128) void emb_v_kernel(
    const float* __restrict__ x, const float* __restrict__ W,
    const float* __restrict__ bias, float* __restrict__ out_emb,
    float2* __restrict__ Vws)
{
    const int s = blockIdx.x;
    const int t = threadIdx.x;
    __shared__ float emb[EMB];
    __shared__ float ctA[NBLK], stA[NBLK], exA[NBLK], eyA[NBLK];

    if (t < EMB) {
        const float* xr = x + s * 64;
        const float* wr = W + t * 64;
        float acc = bias[t];
        #pragma unroll
        for (int k = 0; k < 64; ++k) acc = fmaf(xr[k], wr[k], acc);
        float e = 1.0f / (1.0f + expf(-acc));
        emb[t] = e;
        out_emb[s * EMB + t] = e;
    }
    __syncthreads();

    if (t < NBLK) {
        float th = emb[2 * t]     * 1.57079632679489662f;  // pi/2
        float ph = emb[2 * t + 1] * 6.28318530717958648f;  // 2*pi
        float st, ct, sp, cp;
        sincosf(th, &st, &ct);
        sincosf(ph, &sp, &cp);
        ctA[t] = ct; stA[t] = st; exA[t] = cp; eyA[t] = sp;
    }
    __syncthreads();

    if (t < NPH) {
        const int c = t;  // column 0..7
        float2 u[MODES];
        #pragma unroll
        for (int m = 0; m < MODES; ++m) {
            u[m].x = (m == c) ? 1.0f : 0.0f;
            u[m].y = 0.0f;
        }
        int bi = 0;
        #pragma unroll
        for (int d = 0; d < 8; ++d) {
            const int off = d & 1;
            const int nb = 8 - off;
            #pragma unroll
            for (int k = 0; k < nb; ++k) {
                float ct = ctA[bi], st = stA[bi], ex = exA[bi], ey = eyA[bi];
                ++bi;
                const int r0 = off + 2 * k;
                float2 u0 = u[r0], u1 = u[r0 + 1];
                float2 n0, n1;
                n0.x = ex * ct * u0.x - ey * ct * u0.y - st * u1.x;
                n0.y = ex * ct * u0.y + ey * ct * u0.x - st * u1.y;
                n1.x = ex * st * u0.x - ey * st * u0.y + ct * u1.x;
                n1.y = ex * st * u0.y + ey * st * u0.x + ct * u1.y;
                u[r0] = n0; u[r0 + 1] = n1;
            }
        }
        #pragma unroll
        for (int m = 0; m < MODES; ++m)
            Vws[(s * MODES + m) * NPH + c] = u[m];
    }
}

// Kernel B: upper-triangular tiles only (K symmetric). 528 blocks of 8x8 pairs.
// 4 threads/pair = (row-half h) x (delta7-half e); cross-lane via DPP quad_perm.
// __launch_bounds__(256, 2): VGPR budget 256 — the grid only supplies ~2
// blocks/CU anyway, and the 128-reg cap at (256,4) forces scratch spills of
// Go/Gp inside the unrolled 64-term region (the suspected 90% stall source).
__global__ __launch_bounds__(256, 2) void perm_kernel(
    const float2* __restrict__ Vws, float* __restrict__ outK)
{
    __shared__ float2 sva[8][132];
    __shared__ float2 svb[8][132];

    // triangular decode: blockIdx -> (ta, tb), ta <= tb
    const int L = blockIdx.x;
    int t = (int)((65.0f - sqrtf(4225.0f - 8.0f * (float)L)) * 0.5f);
    while (t * (65 - t) / 2 > L) --t;
    while ((t + 1) * (65 - (t + 1)) / 2 <= L) ++t;
    const int ta = t;
    const int tb = ta + (L - t * (65 - t) / 2);

    const int tid = threadIdx.x;
    const float4* srcA = (const float4*)(Vws + (size_t)ta * 8 * 128);
    const float4* srcB = (const float4*)(Vws + (size_t)tb * 8 * 128);
    #pragma unroll
    for (int r = 0; r < 2; ++r) {
        int idx = r * 256 + tid;       // 0..511
        int row = idx >> 6;
        int c4  = idx & 63;
        *(float4*)&sva[row][c4 * 2] = srcA[idx];
        *(float4*)&svb[row][c4 * 2] = srcB[idx];
    }
    __syncthreads();

    const int p   = tid >> 2;    // pair 0..63 (quad-aligned lanes)
    const int sub = tid & 3;
    const int h   = sub & 1;     // row half
    const int e   = sub >> 1;    // delta7 half
    const int pa  = p >> 3;
    const int pb  = p & 7;

    // ---- build own 2 rows: rows 4h+2e, 4h+2e+1 of G = Va^H Vb ----
    v2f Go[2][8];
    #pragma unroll
    for (int i = 0; i < 2; ++i)
        #pragma unroll
        for (int j = 0; j < 8; ++j) Go[i][j] = (v2f){0.f, 0.f};

    #pragma unroll 2
    for (int m = 0; m < 16; ++m) {
        float4 va4 = *(const float4*)&sva[pa][m * 8 + 4 * h + 2 * e];
        v2f a0 = {va4.x, va4.y};
        v2f a1 = {va4.z, va4.w};
        v2f vb[8];
        #pragma unroll
        for (int jj = 0; jj < 4; ++jj) {
            float4 b4 = *(const float4*)&svb[pb][m * 8 + 2 * jj];
            vb[2 * jj]     = (v2f){b4.x, b4.y};
            vb[2 * jj + 1] = (v2f){b4.z, b4.w};
        }
        #pragma unroll
        for (int j = 0; j < 8; ++j) {
            Go[0][j] = cfma_conj(a0, vb[j], Go[0][j]);
            Go[1][j] = cfma_conj(a1, vb[j], Go[1][j]);
        }
    }

    // ---- exchange 2 rows with delta-partner (xor 2) via DPP ----
    v2f Gp[2][8];
    #pragma unroll
    for (int i = 0; i < 2; ++i)
        #pragma unroll
        for (int j = 0; j < 8; ++j) {
            Gp[i][j].x = dpp_xor2(Go[i][j].x);
            Gp[i][j].y = dpp_xor2(Go[i][j].y);
        }

    // ---- rs init: delta = (+1,...,+1, sgn_e) ----
    const float sgn = 1.0f - 2.0f * (float)e;
    const v2f sgnv = {sgn, sgn};
    v2f rs[4];
    #pragma unroll
    for (int r = 0; r < 2; ++r) {
        {
            v2f s = ((Go[r][0] + Go[r][1]) + (Go[r][2] + Go[r][3]))
                  + ((Go[r][4] + Go[r][5]) + Go[r][6]);
            rs[r] = sgnv * Go[r][7] + s;
        }
        {
            v2f s = ((Gp[r][0] + Gp[r][1]) + (Gp[r][2] + Gp[r][3]))
                  + ((Gp[r][4] + Gp[r][5]) + Gp[r][6]);
            rs[2 + r] = sgnv * Gp[r][7] + s;
        }
    }

    v2f acc;

#define TREE(OUT) do {                                                \
        v2f t01 = cmul(rs[0], rs[1]);                                 \
        v2f t23 = cmul(rs[2], rs[3]);                                 \
        v2f half = cmul(t01, t23);                                    \
        v2f oth;                                                      \
        oth.x = dpp_xor1(half.x);                                     \
        oth.y = dpp_xor1(half.y);                                     \
        OUT = cmul(half, oth);                                        \
    } while (0)

#define UPD(J, S) do {                                                \
        const v2f sv = {(S), (S)};                                    \
        rs[0] = sv * Go[0][J] + rs[0];                                \
        rs[1] = sv * Go[1][J] + rs[1];                                \
        rs[2] = sv * Gp[0][J] + rs[2];                                \
        rs[3] = sv * Gp[1][J] + rs[3];                                \
    } while (0)

#define TERM(TS) do {                                                 \
        v2f fullp; TREE(fullp);                                       \
        const v2f tv = {(TS), (TS)};                                  \
        acc = tv * fullp + acc;                                       \
    } while (0)

    TREE(acc);                              // t=0, sign +
    UPD(1, -2.f); TERM(-1.f);               // t=1
    UPD(2, -2.f); TERM( 1.f);               // t=2
    UPD(1,  2.f); TERM(-1.f);               // t=3
    UPD(3, -2.f); TERM( 1.f);               // t=4
    UPD(1, -2.f); TERM(-1.f);               // t=5
    UPD(2,  2.f); TERM( 1.f);               // t=6
    UPD(1,  2.f); TERM(-1.f);               // t=7
    UPD(4, -2.f); TERM( 1.f);               // t=8
    UPD(1, -2.f); TERM(-1.f);               // t=9
    UPD(2, -2.f); TERM( 1.f);               // t=10
    UPD(1,  2.f); TERM(-1.f);               // t=11
    UPD(3,  2.f); TERM( 1.f);               // t=12
    UPD(1, -2.f); TERM(-1.f);               // t=13
    UPD(2,  2.f); TERM( 1.f);               // t=14
    UPD(1,  2.f); TERM(-1.f);               // t=15
    UPD(5, -2.f); TERM( 1.f);               // t=16
    UPD(1, -2.f); TERM(-1.f);               // t=17
    UPD(2, -2.f); TERM( 1.f);               // t=18
    UPD(1,  2.f); TERM(-1.f);               // t=19
    UPD(3, -2.f); TERM( 1.f);               // t=20
    UPD(1, -2.f); TERM(-1.f);               // t=21
    UPD(2,  2.f); TERM( 1.f);               // t=22
    UPD(1,  2.f); TERM(-1.f);               // t=23
    UPD(4,  2.f); TERM( 1.f);               // t=24
    UPD(1, -2.f); TERM(-1.f);               // t=25
    UPD(2, -2.f); TERM( 1.f);               // t=26
    UPD(1,  2.f); TERM(-1.f);               // t=27
    UPD(3,  2.f); TERM( 1.f);               // t=28
    UPD(1, -2.f); TERM(-1.f);               // t=29
    UPD(2,  2.f); TERM( 1.f);               // t=30
    UPD(1,  2.f); TERM(-1.f);               // t=31
    UPD(6, -2.f); TERM( 1.f);               // t=32
    UPD(1, -2.f); TERM(-1.f);               // t=33
    UPD(2, -2.f); TERM( 1.f);               // t=34
    UPD(1,  2.f); TERM(-1.f);               // t=35
    UPD(3, -2.f); TERM( 1.f);               // t=36
    UPD(1, -2.f); TERM(-1.f);               // t=37
    UPD(2,  2.f); TERM( 1.f);               // t=38
    UPD(1,  2.f); TERM(-1.f);               // t=39
    UPD(4, -2.f); TERM( 1.f);               // t=40
    UPD(1, -2.f); TERM(-1.f);               // t=41
    UPD(2, -2.f); TERM( 1.f);               // t=42
    UPD(1,  2.f); TERM(-1.f);               // t=43
    UPD(3,  2.f); TERM( 1.f);               // t=44
    UPD(1, -2.f); TERM(-1.f);               // t=45
    UPD(2,  2.f); TERM( 1.f);               // t=46
    UPD(1,  2.f); TERM(-1.f);               // t=47
    UPD(5,  2.f); TERM( 1.f);               // t=48
    UPD(1, -2.f); TERM(-1.f);               // t=49
    UPD(2, -2.f); TERM( 1.f);               // t=50
    UPD(1,  2.f); TERM(-1.f);               // t=51
    UPD(3, -2.f); TERM( 1.f);               // t=52
    UPD(1, -2.f); TERM(-1.f);               // t=53
    UPD(2,  2.f); TERM( 1.f);               // t=54
    UPD(1,  2.f); TERM(-1.f);               // t=55
    UPD(4,  2.f); TERM( 1.f);               // t=56
    UPD(1, -2.f); TERM(-1.f);               // t=57
    UPD(2, -2.f); TERM( 1.f);               // t=58
    UPD(1,  2.f); TERM(-1.f);               // t=59
    UPD(3,  2.f); TERM( 1.f);               // t=60
    UPD(1, -2.f); TERM(-1.f);               // t=61
    UPD(2,  2.f); TERM( 1.f);               // t=62
    UPD(1,  2.f); TERM(-1.f);               // t=63
#undef UPD
#undef TERM
#undef TREE

    // fold delta7 sign, then combine the two delta-halves (xor 2, DPP)
    float ax = sgn * acc.x, ay = sgn * acc.y;
    ax += dpp_xor2(ax);
    ay += dpp_xor2(ay);

    if (sub == 0) {
        const int a = ta * 8 + pa;
        const int b = tb * 8 + pb;
        float K = fmaf(ax, ax, ay * ay) * (1.0f / 16384.0f);
        if (a == b) K = 1.0f;
        outK[a * 256 + b] = K;
        outK[b * 256 + a] = K;   // Hermitian symmetry
    }
}

extern "C" void kernel_launch(void* const* d_in, const int* in_sizes, int n_in,
                              void* d_out, int out_size, void* d_ws, size_t ws_size,
                              hipStream_t stream) {
    const float* x    = (const float*)d_in[0];   // 256*64
    const float* W    = (const float*)d_in[1];   // 120*64
    const float* bias = (const float*)d_in[2];   // 120
    float* out     = (float*)d_out;
    float* out_emb = out;              // 256*120
    float* outK    = out + NS * EMB;   // 256*256
    float2* Vws    = (float2*)d_ws;    // 256*16*8 float2 = 256 KB

    emb_v_kernel<<<NS, 128, 0, stream>>>(x, W, bias, out_emb, Vws);
    perm_kernel<<<528, 256, 0, stream>>>(Vws, outK);
}